// Round 1
// baseline (1503.056 us; speedup 1.0000x reference)
//
#include <hip/hip_runtime.h>
#include <math.h>

#define T_TOK 16384
#define DH 768
#define DF 2048
#define NE 8

typedef __attribute__((ext_vector_type(8))) short bf16x8;
typedef __attribute__((ext_vector_type(4))) float f32x4;

__device__ __forceinline__ unsigned short f2bf(float f) {
  union { float f; unsigned int u; } v; v.f = f;
  unsigned int u = v.u;
  u += 0x7fffu + ((u >> 16) & 1u);   // round-to-nearest-even
  return (unsigned short)(u >> 16);
}

__device__ __forceinline__ float gelu_exact(float x) {
  return 0.5f * x * (1.0f + erff(x * 0.70710678118654752440f));
}

// async global->LDS, 16B per lane; lds ptr must be wave-uniform (HW adds lane*16)
__device__ __forceinline__ void async_cp16(void* lds, const void* g) {
  __builtin_amdgcn_global_load_lds(
      (const __attribute__((address_space(1))) unsigned int*)(unsigned long long)g,
      (__attribute__((address_space(3))) unsigned int*)(unsigned int)(unsigned long long)lds,
      16, 0, 0);
}

// ---------------------------------------------------------------------------
// fp32 -> bf16 conversion (vectorized)
__global__ __launch_bounds__(256) void conv_f32_bf16(
    const float* __restrict__ src, unsigned short* __restrict__ dst, int n4) {
  int i = blockIdx.x * blockDim.x + threadIdx.x;
  if (i >= n4) return;
  const float4 v = ((const float4*)src)[i];
  union { unsigned short us[4]; unsigned long long u64; } o;
  o.us[0] = f2bf(v.x); o.us[1] = f2bf(v.y); o.us[2] = f2bf(v.z); o.us[3] = f2bf(v.w);
  ((unsigned long long*)dst)[i] = o.u64;
}

// ---------------------------------------------------------------------------
// gate: per-token logits (fp32, exact), top-2, renormalized softmax weights,
// bucket build via atomics; also converts x -> bf16.
__global__ __launch_bounds__(256) void gate_kernel(
    const float* __restrict__ x, const float* __restrict__ gw,
    unsigned short* __restrict__ xb, int* __restrict__ counts,
    int* __restrict__ tok_list, float* __restrict__ wt_list) {
  const int wave = threadIdx.x >> 6;
  const int lane = threadIdx.x & 63;
  const int t = blockIdx.x * 4 + wave;
  float xv[12];
#pragma unroll
  for (int i = 0; i < 12; ++i) {
    const int c = i * 64 + lane;
    const float v = x[(long)t * DH + c];
    xv[i] = v;
    xb[(long)t * DH + c] = f2bf(v);
  }
  float s[NE];
#pragma unroll
  for (int e = 0; e < NE; ++e) {
    float a = 0.f;
#pragma unroll
    for (int i = 0; i < 12; ++i) a += xv[i] * gw[e * DH + i * 64 + lane];
    s[e] = a;
  }
#pragma unroll
  for (int off = 32; off >= 1; off >>= 1) {
#pragma unroll
    for (int e = 0; e < NE; ++e) s[e] += __shfl_xor(s[e], off);
  }
  if (lane == 0) {
    // top-2 on logits (softmax is monotone); strict > => lowest index on ties
    float b1 = s[0]; int i1 = 0;
#pragma unroll
    for (int e = 1; e < NE; ++e) { if (s[e] > b1) { b1 = s[e]; i1 = e; } }
    float b2 = -3.4e38f; int i2 = 0;
#pragma unroll
    for (int e = 0; e < NE; ++e) {
      if (e != i1 && s[e] > b2) { b2 = s[e]; i2 = e; }
    }
    // renormalized top-2 weights == 2-way softmax over top-2 logits
    const float ex = expf(b2 - b1);
    const float w1 = 1.f / (1.f + ex);
    const float w2 = ex / (1.f + ex);
    int p = atomicAdd(&counts[i1], 1);
    tok_list[i1 * T_TOK + p] = t;
    wt_list[i1 * T_TOK + p] = w1;
    p = atomicAdd(&counts[i2], 1);
    tok_list[i2 * T_TOK + p] = t;
    wt_list[i2 * T_TOK + p] = w2;
  }
}

// ---------------------------------------------------------------------------
// m97-style 128x128 bf16 MFMA GEMM, C = A[MxK] @ W[NxK]^T, with mode epilogues:
//  MODE 0: shared fc1 dual-B: h = gelu(A@B1^T+b1) * (A@B2^T+b3)  -> outH (bf16)
//  MODE 1: routed fc1 (A rows gathered via tok_list): h = gelu(acc+b) -> outH
//  MODE 2: shared fc2: out = acc + b  -> outF (fp32, d_out)
//  MODE 3: routed fc2: out[tok] += w * (acc + b)  (RMW scatter)
template <int MODE>
__global__ __launch_bounds__(256, 2) void gemm_k(
    const unsigned short* __restrict__ A, const unsigned short* __restrict__ B1,
    const unsigned short* __restrict__ B2, const float* __restrict__ bias1,
    const float* __restrict__ bias2, float* __restrict__ outF,
    unsigned short* __restrict__ outH, int K, const int* __restrict__ counts,
    const int* __restrict__ tok_list, const float* __restrict__ wt_list,
    int expert) {
  const int tid = threadIdx.x;
  const int wave = tid >> 6;
  const int lane = tid & 63;
  const int wm = wave >> 1, wn = wave & 1;
  const int l16 = lane & 15, quad = lane >> 4;
  const int n0 = blockIdx.x * 128;
  const int m0 = blockIdx.y * 128;

  int cnt = 0;
  if (MODE == 1 || MODE == 3) {
    cnt = counts[expert];
    const int cnt128 = (cnt + 127) & ~127;
    if (m0 >= cnt128) return;   // block-uniform exit, before any barrier
  }

  __shared__ __align__(16) unsigned short As[128 * 32];
  __shared__ __align__(16) unsigned short Bs[128 * 32];
  __shared__ __align__(16) unsigned short Cs[(MODE == 0) ? 128 * 32 : 16];

  // staging: 2 rounds x 4 waves x 64 lanes x 16B = 8KB tile; round r covers
  // rows r*64 + wave*16 + lane/4, cols (lane&3)*8 .. +7
  const int srow0 = wave * 16 + (lane >> 2);
  const int srow1 = 64 + srow0;
  const int scol = (lane & 3) * 8;

  long ar0, ar1;
  if (MODE == 1) {
    const int p0 = m0 + srow0, p1 = m0 + srow1;
    const int t0 = (p0 < cnt) ? tok_list[expert * T_TOK + p0] : 0;
    const int t1 = (p1 < cnt) ? tok_list[expert * T_TOK + p1] : 0;
    ar0 = (long)t0 * K; ar1 = (long)t1 * K;
  } else {
    ar0 = (long)(m0 + srow0) * K;
    ar1 = (long)(m0 + srow1) * K;
  }
  const unsigned short* ap0 = A + ar0 + scol;
  const unsigned short* ap1 = A + ar1 + scol;
  const unsigned short* bp0 = B1 + (long)(n0 + srow0) * K + scol;
  const unsigned short* bp1 = B1 + (long)(n0 + srow1) * K + scol;
  const unsigned short* cp0 = nullptr; const unsigned short* cp1 = nullptr;
  if constexpr (MODE == 0) {
    cp0 = B2 + (long)(n0 + srow0) * K + scol;
    cp1 = B2 + (long)(n0 + srow1) * K + scol;
  }

  unsigned short* AsW = &As[wave * 512];   // wave-uniform LDS staging base
  unsigned short* BsW = &Bs[wave * 512];
  unsigned short* CsW = nullptr;
  if constexpr (MODE == 0) CsW = &Cs[wave * 512];

  f32x4 acc[4][4];
  f32x4 acc2[(MODE == 0) ? 4 : 1][(MODE == 0) ? 4 : 1];
#pragma unroll
  for (int i = 0; i < 4; ++i) {
#pragma unroll
    for (int j = 0; j < 4; ++j) {
      acc[i][j] = {0.f, 0.f, 0.f, 0.f};
      if constexpr (MODE == 0) acc2[i][j] = {0.f, 0.f, 0.f, 0.f};
    }
  }

  const int KT = K >> 5;
  for (int kt = 0; kt < KT; ++kt) {
    const int ko = kt << 5;
    async_cp16(AsW,        ap0 + ko);
    async_cp16(AsW + 2048, ap1 + ko);
    async_cp16(BsW,        bp0 + ko);
    async_cp16(BsW + 2048, bp1 + ko);
    if constexpr (MODE == 0) {
      async_cp16(CsW,        cp0 + ko);
      async_cp16(CsW + 2048, cp1 + ko);
    }
    __syncthreads();   // drains vmcnt -> staged data visible

    bf16x8 af[4], bfr[4], cfr[(MODE == 0) ? 4 : 1];
#pragma unroll
    for (int mi = 0; mi < 4; ++mi)
      af[mi] = *(const bf16x8*)&As[(wm * 64 + mi * 16 + l16) * 32 + quad * 8];
#pragma unroll
    for (int ni = 0; ni < 4; ++ni) {
      bfr[ni] = *(const bf16x8*)&Bs[(wn * 64 + ni * 16 + l16) * 32 + quad * 8];
      if constexpr (MODE == 0)
        cfr[ni] = *(const bf16x8*)&Cs[(wn * 64 + ni * 16 + l16) * 32 + quad * 8];
    }
#pragma unroll
    for (int mi = 0; mi < 4; ++mi) {
#pragma unroll
      for (int ni = 0; ni < 4; ++ni) {
        acc[mi][ni] = __builtin_amdgcn_mfma_f32_16x16x32_bf16(
            af[mi], bfr[ni], acc[mi][ni], 0, 0, 0);
        if constexpr (MODE == 0)
          acc2[mi][ni] = __builtin_amdgcn_mfma_f32_16x16x32_bf16(
              af[mi], cfr[ni], acc2[mi][ni], 0, 0, 0);
      }
    }
    __syncthreads();   // compute done before next overwrite
  }

  // epilogue; C/D layout: row = quad*4 + reg, col = lane&15 (m89-verified)
#pragma unroll
  for (int mi = 0; mi < 4; ++mi) {
#pragma unroll
    for (int r = 0; r < 4; ++r) {
      const int row = m0 + wm * 64 + mi * 16 + quad * 4 + r;
      if constexpr (MODE == 3) {
        if (row < cnt) {
          const int t = tok_list[expert * T_TOK + row];
          const float w = wt_list[expert * T_TOK + row];
#pragma unroll
          for (int ni = 0; ni < 4; ++ni) {
            const int c = n0 + wn * 64 + ni * 16 + l16;
            float* o = outF + (long)t * DH + c;
            *o += w * (acc[mi][ni][r] + bias1[c]);
          }
        }
      } else if constexpr (MODE == 2) {
#pragma unroll
        for (int ni = 0; ni < 4; ++ni) {
          const int c = n0 + wn * 64 + ni * 16 + l16;
          outF[(long)row * DH + c] = acc[mi][ni][r] + bias1[c];
        }
      } else if constexpr (MODE == 1) {
#pragma unroll
        for (int ni = 0; ni < 4; ++ni) {
          const int c = n0 + wn * 64 + ni * 16 + l16;
          outH[(long)row * DF + c] = f2bf(gelu_exact(acc[mi][ni][r] + bias1[c]));
        }
      } else {
#pragma unroll
        for (int ni = 0; ni < 4; ++ni) {
          const int c = n0 + wn * 64 + ni * 16 + l16;
          const float h1 = acc[mi][ni][r] + bias1[c];
          const float h3 = acc2[mi][ni][r] + bias2[c];
          outH[(long)row * DF + c] = f2bf(gelu_exact(h1) * h3);
        }
      }
    }
  }
}

// ---------------------------------------------------------------------------
extern "C" void kernel_launch(void* const* d_in, const int* in_sizes, int n_in,
                              void* d_out, int out_size, void* d_ws, size_t ws_size,
                              hipStream_t stream) {
  const float* x     = (const float*)d_in[0];
  const float* gw    = (const float*)d_in[1];
  const float* fc1w  = (const float*)d_in[2];
  const float* fc1bs = (const float*)d_in[3];
  const float* fc2w  = (const float*)d_in[4];
  const float* fc2bs = (const float*)d_in[5];
  const float* w1w   = (const float*)d_in[6];
  const float* w1bs  = (const float*)d_in[7];
  const float* w3w   = (const float*)d_in[8];
  const float* w3bs  = (const float*)d_in[9];
  const float* w2w   = (const float*)d_in[10];
  const float* w2bs  = (const float*)d_in[11];
  float* out = (float*)d_out;

  char* p = (char*)d_ws;
  auto take = [&](size_t b) { char* r = p; p += (b + 255) & ~(size_t)255; return r; };
  unsigned short* xb   = (unsigned short*)take((size_t)T_TOK * DH * 2);
  unsigned short* fc1b = (unsigned short*)take((size_t)NE * DF * DH * 2);
  unsigned short* fc2b = (unsigned short*)take((size_t)NE * DH * DF * 2);
  unsigned short* w1b  = (unsigned short*)take((size_t)DF * DH * 2);
  unsigned short* w3b  = (unsigned short*)take((size_t)DF * DH * 2);
  unsigned short* w2b  = (unsigned short*)take((size_t)DH * DF * 2);
  unsigned short* h    = (unsigned short*)take((size_t)T_TOK * DF * 2);
  int*   counts   = (int*)take(256);
  int*   tok_list = (int*)take((size_t)NE * T_TOK * 4);
  float* wt_list  = (float*)take((size_t)NE * T_TOK * 4);
  // total ws use: ~150 MB

  hipMemsetAsync(counts, 0, NE * sizeof(int), stream);

  auto conv = [&](const float* s, unsigned short* d, long n) {
    int n4 = (int)(n >> 2);
    conv_f32_bf16<<<(n4 + 255) / 256, 256, 0, stream>>>(s, d, n4);
  };
  conv(fc1w, fc1b, (long)NE * DF * DH);
  conv(fc2w, fc2b, (long)NE * DH * DF);
  conv(w1w, w1b, (long)DF * DH);
  conv(w3w, w3b, (long)DF * DH);
  conv(w2w, w2b, (long)DH * DF);

  gate_kernel<<<T_TOK / 4, 256, 0, stream>>>(x, gw, xb, counts, tok_list, wt_list);

  // shared MLP: h = gelu(x@w1^T+b1)*(x@w3^T+b3); out = h@w2^T + b2
  gemm_k<0><<<dim3(DF / 128, T_TOK / 128), 256, 0, stream>>>(
      xb, w1b, w3b, w1bs, w3bs, nullptr, h, DH, nullptr, nullptr, nullptr, 0);
  gemm_k<2><<<dim3(DH / 128, T_TOK / 128), 256, 0, stream>>>(
      h, w2b, nullptr, w2bs, nullptr, out, nullptr, DF, nullptr, nullptr, nullptr, 0);

  // routed experts, sequential pairs over reused h buffer
  for (int e = 0; e < NE; ++e) {
    gemm_k<1><<<dim3(DF / 128, T_TOK / 128), 256, 0, stream>>>(
        xb, fc1b + (size_t)e * DF * DH, nullptr, fc1bs + (size_t)e * DF, nullptr,
        nullptr, h, DH, counts, tok_list, nullptr, e);
    gemm_k<3><<<dim3(DH / 128, T_TOK / 128), 256, 0, stream>>>(
        h, fc2b + (size_t)e * DH * DF, nullptr, fc2bs + (size_t)e * DH, nullptr,
        out, nullptr, DF, counts, tok_list, wt_list, e);
  }
}

// Round 2
// 851.102 us; speedup vs baseline: 1.7660x; 1.7660x over previous
//
#include <hip/hip_runtime.h>
#include <math.h>

#define T_TOK 16384
#define DH 768
#define DF 2048
#define NE 8
#define NSLOT (2 * T_TOK)          // 32768 routed (token,slot) entries
#define MT_ROUTED 264              // ceil((NSLOT + 8*127)/128) m-tiles, padded worst case
#define NROW_H (MT_ROUTED * 128)   // 33792 rows in routed h buffer

typedef __attribute__((ext_vector_type(8))) short bf16x8;
typedef __attribute__((ext_vector_type(4))) float f32x4;

__device__ __forceinline__ unsigned short f2bf(float f) {
  union { float f; unsigned int u; } v; v.f = f;
  unsigned int u = v.u;
  u += 0x7fffu + ((u >> 16) & 1u);   // round-to-nearest-even
  return (unsigned short)(u >> 16);
}

__device__ __forceinline__ float gelu_exact(float x) {
  return 0.5f * x * (1.0f + erff(x * 0.70710678118654752440f));
}

// async global->LDS, 16B per lane; lds ptr must be wave-uniform (HW adds lane*16)
__device__ __forceinline__ void async_cp16(void* lds, const void* g) {
  __builtin_amdgcn_global_load_lds(
      (const __attribute__((address_space(1))) unsigned int*)(unsigned long long)g,
      (__attribute__((address_space(3))) unsigned int*)(unsigned int)(unsigned long long)lds,
      16, 0, 0);
}

// ---------------------------------------------------------------------------
// fp32 -> bf16 conversion (vectorized)
__global__ __launch_bounds__(256) void conv_f32_bf16(
    const float* __restrict__ src, unsigned short* __restrict__ dst, int n4) {
  int i = blockIdx.x * blockDim.x + threadIdx.x;
  if (i >= n4) return;
  const float4 v = ((const float4*)src)[i];
  union { unsigned short us[4]; unsigned long long u64; } o;
  o.us[0] = f2bf(v.x); o.us[1] = f2bf(v.y); o.us[2] = f2bf(v.z); o.us[3] = f2bf(v.w);
  ((unsigned long long*)dst)[i] = o.u64;
}

// ---------------------------------------------------------------------------
// gate phase A: per-token logits (fp32), top-2, renorm weights. NO atomics.
// Also converts x -> bf16. One wave per token.
__global__ __launch_bounds__(256) void gate_topk(
    const float* __restrict__ x, const float* __restrict__ gw,
    unsigned short* __restrict__ xb, int* __restrict__ eids,
    float* __restrict__ wts) {
  const int wave = threadIdx.x >> 6;
  const int lane = threadIdx.x & 63;
  const int t = blockIdx.x * 4 + wave;
  float4 xv[3];
#pragma unroll
  for (int i = 0; i < 3; ++i) {
    const int c = i * 256 + lane * 4;
    xv[i] = *(const float4*)&x[(long)t * DH + c];
    ushort4 o;
    o.x = f2bf(xv[i].x); o.y = f2bf(xv[i].y);
    o.z = f2bf(xv[i].z); o.w = f2bf(xv[i].w);
    *(ushort4*)&xb[(long)t * DH + c] = o;
  }
  float s[NE];
#pragma unroll
  for (int e = 0; e < NE; ++e) {
    float a = 0.f;
#pragma unroll
    for (int i = 0; i < 3; ++i) {
      const float4 g = *(const float4*)&gw[e * DH + i * 256 + lane * 4];
      a += xv[i].x * g.x + xv[i].y * g.y + xv[i].z * g.z + xv[i].w * g.w;
    }
    s[e] = a;
  }
#pragma unroll
  for (int off = 32; off >= 1; off >>= 1) {
#pragma unroll
    for (int e = 0; e < NE; ++e) s[e] += __shfl_xor(s[e], off);
  }
  if (lane == 0) {
    float b1 = s[0]; int i1 = 0;
#pragma unroll
    for (int e = 1; e < NE; ++e) { if (s[e] > b1) { b1 = s[e]; i1 = e; } }
    float b2 = -3.4e38f; int i2 = 0;
#pragma unroll
    for (int e = 0; e < NE; ++e) {
      if (e != i1 && s[e] > b2) { b2 = s[e]; i2 = e; }
    }
    const float ex = expf(b2 - b1);
    eids[2 * t]     = i1; wts[2 * t]     = 1.f / (1.f + ex);
    eids[2 * t + 1] = i2; wts[2 * t + 1] = ex / (1.f + ex);
  }
}

// ---------------------------------------------------------------------------
// gate phase B: histogram with ballot aggregation; counters padded 256B apart
__global__ __launch_bounds__(256) void hist_k(
    const int* __restrict__ eids, int* __restrict__ hcur) {
  const int j = blockIdx.x * 256 + threadIdx.x;
  const int lane = threadIdx.x & 63;
  const int eid = eids[j];
#pragma unroll
  for (int e = 0; e < NE; ++e) {
    const unsigned long long m = __ballot(eid == e);
    const int tot = __popcll(m);
    if (tot && lane == (__ffsll((long long)m) - 1)) atomicAdd(&hcur[e * 64], tot);
  }
}

// gate phase C: exclusive scan of 128-padded counts (1 thread, 8 elems)
__global__ void scan_k(const int* __restrict__ hcur, int* __restrict__ sched,
                       int* __restrict__ cur2) {
  if (threadIdx.x == 0) {
    int b = 0;
#pragma unroll
    for (int e = 0; e < NE; ++e) {
      const int c = hcur[e * 64];
      sched[e] = b; sched[9 + e] = c; cur2[e * 64] = b;
      b += (c + 127) & ~127;
    }
    sched[8] = b;
  }
}

// gate phase D: scatter entries into compacted per-expert slots
__global__ __launch_bounds__(256) void scatter_k(
    const int* __restrict__ eids, const float* __restrict__ wts,
    int* __restrict__ cur2, int* __restrict__ slot_tok,
    float* __restrict__ slot_wt) {
  const int j = blockIdx.x * 256 + threadIdx.x;
  const int lane = threadIdx.x & 63;
  const int eid = eids[j];
  const float w = wts[j];
#pragma unroll
  for (int e = 0; e < NE; ++e) {
    const unsigned long long m = __ballot(eid == e);
    const int tot = __popcll(m);
    if (!tot) continue;                      // wave-uniform branch
    const int leader = __ffsll((long long)m) - 1;
    int b = 0;
    if (lane == leader) b = atomicAdd(&cur2[e * 64], tot);
    b = __shfl(b, leader);
    if (eid == e) {
      const int pos = b + __popcll(m & ((1ull << lane) - 1));
      slot_tok[pos] = j;                     // token = j>>1
      slot_wt[pos] = w;
    }
  }
}

// ---------------------------------------------------------------------------
// m97-style 128x128 bf16 MFMA GEMM, C = A[MxK] @ W[NxK]^T, with mode epilogues:
//  MODE 0: shared fc1 dual-B: h = gelu(A@B1^T+b1) * (A@B2^T+b3)  -> outH (bf16)
//  MODE 1: routed fc1, all experts in one launch, A rows gathered via slot_tok
//  MODE 2: shared fc2: out = acc + b  -> outF (fp32, d_out)
//  MODE 3: routed fc2, all experts: atomicAdd(out[tok], w * (acc + b))
template <int MODE>
__global__ __launch_bounds__(256, 2) void gemm_k(
    const unsigned short* __restrict__ A, const unsigned short* __restrict__ B1,
    const unsigned short* __restrict__ B2, const float* __restrict__ bias1,
    const float* __restrict__ bias2, float* __restrict__ outF,
    unsigned short* __restrict__ outH, int K,
    const int* __restrict__ sched, const int* __restrict__ slot_tok,
    const float* __restrict__ slot_wt) {
  const int tid = threadIdx.x;
  const int wave = tid >> 6;
  const int lane = tid & 63;
  const int wm = wave >> 1, wn = wave & 1;
  const int l16 = lane & 15, quad = lane >> 4;
  const int n0 = blockIdx.x * 128;
  const int m0 = blockIdx.y * 128;

  const unsigned short* Bbase = B1;
  const float* bias = bias1;
  int cnt_end = 0;
  if constexpr (MODE == 1 || MODE == 3) {
    if (m0 >= sched[8]) return;              // block-uniform exit, no barriers yet
    int e = 0;
#pragma unroll
    for (int i = 1; i < NE; ++i) { if (m0 >= sched[i]) e = i; }
    cnt_end = sched[e] + sched[9 + e];       // base[e] + count[e]
    Bbase = B1 + (long)e * ((MODE == 1) ? (long)DF * DH : (long)DH * DF);
    bias = bias1 + e * ((MODE == 1) ? DF : DH);
  }

  __shared__ __align__(16) unsigned short As[128 * 32];
  __shared__ __align__(16) unsigned short Bs[128 * 32];
  __shared__ __align__(16) unsigned short Cs[(MODE == 0) ? 128 * 32 : 16];

  const int srow0 = wave * 16 + (lane >> 2);
  const int srow1 = 64 + srow0;
  const int scol = (lane & 3) * 8;

  long ar0, ar1;
  if constexpr (MODE == 1) {
    const int p0 = m0 + srow0, p1 = m0 + srow1;
    const int t0 = (p0 < cnt_end) ? (slot_tok[p0] >> 1) : 0;
    const int t1 = (p1 < cnt_end) ? (slot_tok[p1] >> 1) : 0;
    ar0 = (long)t0 * K; ar1 = (long)t1 * K;
  } else {
    ar0 = (long)(m0 + srow0) * K;
    ar1 = (long)(m0 + srow1) * K;
  }
  const unsigned short* ap0 = A + ar0 + scol;
  const unsigned short* ap1 = A + ar1 + scol;
  const unsigned short* bp0 = Bbase + (long)(n0 + srow0) * K + scol;
  const unsigned short* bp1 = Bbase + (long)(n0 + srow1) * K + scol;
  const unsigned short* cp0 = nullptr; const unsigned short* cp1 = nullptr;
  if constexpr (MODE == 0) {
    cp0 = B2 + (long)(n0 + srow0) * K + scol;
    cp1 = B2 + (long)(n0 + srow1) * K + scol;
  }

  unsigned short* AsW = &As[wave * 512];
  unsigned short* BsW = &Bs[wave * 512];
  unsigned short* CsW = nullptr;
  if constexpr (MODE == 0) CsW = &Cs[wave * 512];

  f32x4 acc[4][4];
  f32x4 acc2[(MODE == 0) ? 4 : 1][(MODE == 0) ? 4 : 1];
#pragma unroll
  for (int i = 0; i < 4; ++i) {
#pragma unroll
    for (int j = 0; j < 4; ++j) {
      acc[i][j] = {0.f, 0.f, 0.f, 0.f};
      if constexpr (MODE == 0) acc2[i][j] = {0.f, 0.f, 0.f, 0.f};
    }
  }

  const int KT = K >> 5;
  for (int kt = 0; kt < KT; ++kt) {
    const int ko = kt << 5;
    async_cp16(AsW,        ap0 + ko);
    async_cp16(AsW + 2048, ap1 + ko);
    async_cp16(BsW,        bp0 + ko);
    async_cp16(BsW + 2048, bp1 + ko);
    if constexpr (MODE == 0) {
      async_cp16(CsW,        cp0 + ko);
      async_cp16(CsW + 2048, cp1 + ko);
    }
    __syncthreads();

    bf16x8 af[4], bfr[4], cfr[(MODE == 0) ? 4 : 1];
#pragma unroll
    for (int mi = 0; mi < 4; ++mi)
      af[mi] = *(const bf16x8*)&As[(wm * 64 + mi * 16 + l16) * 32 + quad * 8];
#pragma unroll
    for (int ni = 0; ni < 4; ++ni) {
      bfr[ni] = *(const bf16x8*)&Bs[(wn * 64 + ni * 16 + l16) * 32 + quad * 8];
      if constexpr (MODE == 0)
        cfr[ni] = *(const bf16x8*)&Cs[(wn * 64 + ni * 16 + l16) * 32 + quad * 8];
    }
#pragma unroll
    for (int mi = 0; mi < 4; ++mi) {
#pragma unroll
      for (int ni = 0; ni < 4; ++ni) {
        acc[mi][ni] = __builtin_amdgcn_mfma_f32_16x16x32_bf16(
            af[mi], bfr[ni], acc[mi][ni], 0, 0, 0);
        if constexpr (MODE == 0)
          acc2[mi][ni] = __builtin_amdgcn_mfma_f32_16x16x32_bf16(
              af[mi], cfr[ni], acc2[mi][ni], 0, 0, 0);
      }
    }
    __syncthreads();
  }

  // epilogue; C/D layout: row = quad*4 + reg, col = lane&15 (m89-verified)
#pragma unroll
  for (int mi = 0; mi < 4; ++mi) {
#pragma unroll
    for (int r = 0; r < 4; ++r) {
      const int row = m0 + wm * 64 + mi * 16 + quad * 4 + r;
      if constexpr (MODE == 3) {
        if (row < cnt_end) {
          const int t = slot_tok[row] >> 1;
          const float w = slot_wt[row];
#pragma unroll
          for (int ni = 0; ni < 4; ++ni) {
            const int c = n0 + wn * 64 + ni * 16 + l16;
            atomicAdd(&outF[(long)t * DH + c], w * (acc[mi][ni][r] + bias[c]));
          }
        }
      } else if constexpr (MODE == 2) {
#pragma unroll
        for (int ni = 0; ni < 4; ++ni) {
          const int c = n0 + wn * 64 + ni * 16 + l16;
          outF[(long)row * DH + c] = acc[mi][ni][r] + bias[c];
        }
      } else if constexpr (MODE == 1) {
#pragma unroll
        for (int ni = 0; ni < 4; ++ni) {
          const int c = n0 + wn * 64 + ni * 16 + l16;
          outH[(long)row * DF + c] = f2bf(gelu_exact(acc[mi][ni][r] + bias[c]));
        }
      } else {
#pragma unroll
        for (int ni = 0; ni < 4; ++ni) {
          const int c = n0 + wn * 64 + ni * 16 + l16;
          const float h1 = acc[mi][ni][r] + bias[c];
          const float h3 = acc2[mi][ni][r] + bias2[c];
          outH[(long)row * DF + c] = f2bf(gelu_exact(h1) * h3);
        }
      }
    }
  }
}

// ---------------------------------------------------------------------------
extern "C" void kernel_launch(void* const* d_in, const int* in_sizes, int n_in,
                              void* d_out, int out_size, void* d_ws, size_t ws_size,
                              hipStream_t stream) {
  const float* x     = (const float*)d_in[0];
  const float* gw    = (const float*)d_in[1];
  const float* fc1w  = (const float*)d_in[2];
  const float* fc1bs = (const float*)d_in[3];
  const float* fc2w  = (const float*)d_in[4];
  const float* fc2bs = (const float*)d_in[5];
  const float* w1w   = (const float*)d_in[6];
  const float* w1bs  = (const float*)d_in[7];
  const float* w3w   = (const float*)d_in[8];
  const float* w3bs  = (const float*)d_in[9];
  const float* w2w   = (const float*)d_in[10];
  const float* w2bs  = (const float*)d_in[11];
  float* out = (float*)d_out;

  char* p = (char*)d_ws;
  auto take = [&](size_t b) { char* r = p; p += (b + 255) & ~(size_t)255; return r; };
  unsigned short* xb   = (unsigned short*)take((size_t)T_TOK * DH * 2);
  unsigned short* fc1b = (unsigned short*)take((size_t)NE * DF * DH * 2);
  unsigned short* fc2b = (unsigned short*)take((size_t)NE * DH * DF * 2);
  unsigned short* w1b  = (unsigned short*)take((size_t)DF * DH * 2);
  unsigned short* w3b  = (unsigned short*)take((size_t)DF * DH * 2);
  unsigned short* w2b  = (unsigned short*)take((size_t)DH * DF * 2);
  unsigned short* h    = (unsigned short*)take((size_t)NROW_H * DF * 2);
  int*   eids     = (int*)take((size_t)NSLOT * 4);
  float* wts      = (float*)take((size_t)NSLOT * 4);
  int*   hcur     = (int*)take(NE * 64 * 4);
  int*   cur2     = (int*)take(NE * 64 * 4);
  int*   sched    = (int*)take(32 * 4);
  int*   slot_tok = (int*)take((size_t)NROW_H * 4);
  float* slot_wt  = (float*)take((size_t)NROW_H * 4);
  // total ws use: ~275 MB

  hipMemsetAsync(hcur, 0, NE * 64 * sizeof(int), stream);

  auto conv = [&](const float* s, unsigned short* d, long n) {
    int n4 = (int)(n >> 2);
    conv_f32_bf16<<<(n4 + 255) / 256, 256, 0, stream>>>(s, d, n4);
  };
  conv(fc1w, fc1b, (long)NE * DF * DH);
  conv(fc2w, fc2b, (long)NE * DH * DF);
  conv(w1w, w1b, (long)DF * DH);
  conv(w3w, w3b, (long)DF * DH);
  conv(w2w, w2b, (long)DH * DF);

  // gate: topk (no atomics) -> histogram -> scan -> scatter
  gate_topk<<<T_TOK / 4, 256, 0, stream>>>(x, gw, xb, eids, wts);
  hist_k<<<NSLOT / 256, 256, 0, stream>>>(eids, hcur);
  scan_k<<<1, 64, 0, stream>>>(hcur, sched, cur2);
  scatter_k<<<NSLOT / 256, 256, 0, stream>>>(eids, wts, cur2, slot_tok, slot_wt);

  // shared MLP first (out = plain stores), then routed adds on top (atomic)
  gemm_k<0><<<dim3(DF / 128, T_TOK / 128), 256, 0, stream>>>(
      xb, w1b, w3b, w1bs, w3bs, nullptr, h, DH, nullptr, nullptr, nullptr);
  gemm_k<2><<<dim3(DH / 128, T_TOK / 128), 256, 0, stream>>>(
      h, w2b, nullptr, w2bs, nullptr, out, nullptr, DF, nullptr, nullptr, nullptr);

  // routed experts: ALL experts in one fc1 launch + one fc2 launch
  gemm_k<1><<<dim3(DF / 128, MT_ROUTED), 256, 0, stream>>>(
      xb, fc1b, nullptr, fc1bs, nullptr, nullptr, h, DH, sched, slot_tok, slot_wt);
  gemm_k<3><<<dim3(DH / 128, MT_ROUTED), 256, 0, stream>>>(
      h, fc2b, nullptr, fc2bs, nullptr, out, nullptr, DF, sched, slot_tok, slot_wt);
}

// Round 4
// 774.487 us; speedup vs baseline: 1.9407x; 1.0989x over previous
//
#include <hip/hip_runtime.h>
#include <math.h>

#define T_TOK 16384
#define DH 768
#define DF 2048
#define NE 8
#define NSLOT (2 * T_TOK)          // 32768 routed (token,slot) entries
#define MT_ROUTED 264              // ceil((NSLOT + 8*127)/128) m-tiles, worst case
#define NROW_H (MT_ROUTED * 128)   // 33792 rows in routed h / y buffers

typedef __attribute__((ext_vector_type(8))) short bf16x8;
typedef __attribute__((ext_vector_type(4))) float f32x4;

__device__ __forceinline__ unsigned short f2bf(float f) {
  union { float f; unsigned int u; } v; v.f = f;
  unsigned int u = v.u;
  u += 0x7fffu + ((u >> 16) & 1u);   // round-to-nearest-even
  return (unsigned short)(u >> 16);
}
__device__ __forceinline__ float bf2f(unsigned short s) {
  union { unsigned int u; float f; } v; v.u = ((unsigned int)s) << 16; return v.f;
}

__device__ __forceinline__ float gelu_exact(float x) {
  return 0.5f * x * (1.0f + erff(x * 0.70710678118654752440f));
}

// y buffer is split: rows [0,T_TOK) alias the dead fc1b region, rows
// [T_TOK, NROW_H) live in a small dedicated region (saves 25 MB of ws).
__device__ __forceinline__ unsigned short* yrow(unsigned short* ylo,
                                                unsigned short* yhi, int s) {
  return (s < T_TOK) ? (ylo + (long)s * DH) : (yhi + (long)(s - T_TOK) * DH);
}

// async global->LDS, 16B per lane; lds ptr must be wave-uniform (HW adds lane*16)
__device__ __forceinline__ void async_cp16(void* lds, const void* g) {
  __builtin_amdgcn_global_load_lds(
      (const __attribute__((address_space(1))) unsigned int*)(unsigned long long)g,
      (__attribute__((address_space(3))) unsigned int*)(unsigned int)(unsigned long long)lds,
      16, 0, 0);
}

// ---------------------------------------------------------------------------
__global__ __launch_bounds__(256) void conv_f32_bf16(
    const float* __restrict__ src, unsigned short* __restrict__ dst, int n4) {
  int i = blockIdx.x * blockDim.x + threadIdx.x;
  if (i >= n4) return;
  const float4 v = ((const float4*)src)[i];
  union { unsigned short us[4]; unsigned long long u64; } o;
  o.us[0] = f2bf(v.x); o.us[1] = f2bf(v.y); o.us[2] = f2bf(v.z); o.us[3] = f2bf(v.w);
  ((unsigned long long*)dst)[i] = o.u64;
}

// ---------------------------------------------------------------------------
// gate phase A: per-token logits (fp32), top-2, renorm weights. NO atomics.
__global__ __launch_bounds__(256) void gate_topk(
    const float* __restrict__ x, const float* __restrict__ gw,
    unsigned short* __restrict__ xb, int* __restrict__ eids,
    float* __restrict__ wts) {
  const int wave = threadIdx.x >> 6;
  const int lane = threadIdx.x & 63;
  const int t = blockIdx.x * 4 + wave;
  float4 xv[3];
#pragma unroll
  for (int i = 0; i < 3; ++i) {
    const int c = i * 256 + lane * 4;
    xv[i] = *(const float4*)&x[(long)t * DH + c];
    ushort4 o;
    o.x = f2bf(xv[i].x); o.y = f2bf(xv[i].y);
    o.z = f2bf(xv[i].z); o.w = f2bf(xv[i].w);
    *(ushort4*)&xb[(long)t * DH + c] = o;
  }
  float s[NE];
#pragma unroll
  for (int e = 0; e < NE; ++e) {
    float a = 0.f;
#pragma unroll
    for (int i = 0; i < 3; ++i) {
      const float4 g = *(const float4*)&gw[e * DH + i * 256 + lane * 4];
      a += xv[i].x * g.x + xv[i].y * g.y + xv[i].z * g.z + xv[i].w * g.w;
    }
    s[e] = a;
  }
#pragma unroll
  for (int off = 32; off >= 1; off >>= 1) {
#pragma unroll
    for (int e = 0; e < NE; ++e) s[e] += __shfl_xor(s[e], off);
  }
  if (lane == 0) {
    float b1 = s[0]; int i1 = 0;
#pragma unroll
    for (int e = 1; e < NE; ++e) { if (s[e] > b1) { b1 = s[e]; i1 = e; } }
    float b2 = -3.4e38f; int i2 = 0;
#pragma unroll
    for (int e = 0; e < NE; ++e) {
      if (e != i1 && s[e] > b2) { b2 = s[e]; i2 = e; }
    }
    const float ex = expf(b2 - b1);
    eids[2 * t]     = i1; wts[2 * t]     = 1.f / (1.f + ex);
    eids[2 * t + 1] = i2; wts[2 * t + 1] = ex / (1.f + ex);
  }
}

// gate phase B: histogram with ballot aggregation; counters padded 256B apart
__global__ __launch_bounds__(256) void hist_k(
    const int* __restrict__ eids, int* __restrict__ hcur) {
  const int j = blockIdx.x * 256 + threadIdx.x;
  const int lane = threadIdx.x & 63;
  const int eid = eids[j];
#pragma unroll
  for (int e = 0; e < NE; ++e) {
    const unsigned long long m = __ballot(eid == e);
    const int tot = __popcll(m);
    if (tot && lane == (__ffsll((long long)m) - 1)) atomicAdd(&hcur[e * 64], tot);
  }
}

// gate phase C: exclusive scan of 128-padded counts
__global__ void scan_k(const int* __restrict__ hcur, int* __restrict__ sched,
                       int* __restrict__ cur2) {
  if (threadIdx.x == 0) {
    int b = 0;
#pragma unroll
    for (int e = 0; e < NE; ++e) {
      const int c = hcur[e * 64];
      sched[e] = b; sched[9 + e] = c; cur2[e * 64] = b;
      b += (c + 127) & ~127;
    }
    sched[8] = b;
  }
}

// gate phase D: scatter into compacted per-expert slots + inverse map
__global__ __launch_bounds__(256) void scatter_k(
    const int* __restrict__ eids, const float* __restrict__ wts,
    int* __restrict__ cur2, int* __restrict__ slot_tok,
    float* __restrict__ slot_wt, int* __restrict__ slot_pos) {
  const int j = blockIdx.x * 256 + threadIdx.x;
  const int lane = threadIdx.x & 63;
  const int eid = eids[j];
  const float w = wts[j];
#pragma unroll
  for (int e = 0; e < NE; ++e) {
    const unsigned long long m = __ballot(eid == e);
    const int tot = __popcll(m);
    if (!tot) continue;                      // wave-uniform branch
    const int leader = __ffsll((long long)m) - 1;
    int b = 0;
    if (lane == leader) b = atomicAdd(&cur2[e * 64], tot);
    b = __shfl(b, leader);
    if (eid == e) {
      const int pos = b + __popcll(m & ((1ull << lane) - 1));
      slot_tok[pos] = j;                     // token = j>>1
      slot_wt[pos] = w;
      slot_pos[j] = pos;                     // inverse map for combine
    }
  }
}

// ---------------------------------------------------------------------------
// 128x128 bf16 MFMA GEMM, C = A[MxK] @ W[NxK]^T. XCD-swizzled 1D grid:
// yx = (id%8)*BPX + id/8; x = yx%GX (n-tile, fastest within an XCD -> A-tile
// L2 reuse), y = yx/GX (m-tile).
//  MODE 0: shared fc1 dual-B: h = gelu(A@B1^T+b1)*(A@B2^T+b3) -> outH (bf16)
//  MODE 1: routed fc1 (all experts), A rows gathered via slot_tok -> outH
//  MODE 2: shared fc2 + combine: out = acc+b + w0*y[s0]+w1*y[s1] (plain store)
//  MODE 3: routed fc2 (all experts): y[slot] = acc + b (bf16, plain store)
//  MODE 4: routed fc2 (all experts): atomicAdd(out[tok], w*(acc+b))  [fallback]
//  MODE 5: shared fc2 plain: out = acc + b                           [fallback]
template <int MODE, int GX, int GTOT>
__global__ __launch_bounds__(256, 2) void gemm_k(
    const unsigned short* __restrict__ A, const unsigned short* __restrict__ B1,
    const unsigned short* __restrict__ B2, const float* __restrict__ bias1,
    const float* __restrict__ bias2, float* __restrict__ outF,
    unsigned short* __restrict__ outH, int K,
    const int* __restrict__ sched, const int* __restrict__ slot_tok,
    const int* __restrict__ slot_pos, const float* __restrict__ wts,
    unsigned short* __restrict__ ylo, unsigned short* __restrict__ yhi) {
  constexpr int BPX = (GTOT + 7) / 8;
  const int id = blockIdx.x;
  const int yx = (id & 7) * BPX + (id >> 3);
  const int n0 = (yx % GX) * 128;
  const int m0 = (yx / GX) * 128;

  const int tid = threadIdx.x;
  const int wave = tid >> 6;
  const int lane = tid & 63;
  const int wm = wave >> 1, wn = wave & 1;
  const int l16 = lane & 15, quad = lane >> 4;

  const unsigned short* Bbase = B1;
  const float* bias = bias1;
  int cnt_end = 0;
  if constexpr (MODE == 1 || MODE == 3 || MODE == 4) {
    if (m0 >= sched[8]) return;              // block-uniform exit, no barriers yet
    int e = 0;
#pragma unroll
    for (int i = 1; i < NE; ++i) { if (m0 >= sched[i]) e = i; }
    cnt_end = sched[e] + sched[9 + e];       // base[e] + count[e]
    Bbase = B1 + (long)e * ((long)DF * DH);  // fc1[e] and fc2[e] are both DF*DH
    bias = bias1 + e * ((MODE == 1) ? DF : DH);
  }

  __shared__ __align__(16) unsigned short As[128 * 32];
  __shared__ __align__(16) unsigned short Bs[128 * 32];
  __shared__ __align__(16) unsigned short Cs[(MODE == 0) ? 128 * 32 : 16];

  const int srow0 = wave * 16 + (lane >> 2);
  const int srow1 = 64 + srow0;
  const int scol = (lane & 3) * 8;

  long ar0, ar1;
  if constexpr (MODE == 1) {
    const int p0 = m0 + srow0, p1 = m0 + srow1;
    const int t0 = (p0 < cnt_end) ? (slot_tok[p0] >> 1) : 0;
    const int t1 = (p1 < cnt_end) ? (slot_tok[p1] >> 1) : 0;
    ar0 = (long)t0 * K; ar1 = (long)t1 * K;
  } else {
    ar0 = (long)(m0 + srow0) * K;
    ar1 = (long)(m0 + srow1) * K;
  }
  const unsigned short* ap0 = A + ar0 + scol;
  const unsigned short* ap1 = A + ar1 + scol;
  const unsigned short* bp0 = Bbase + (long)(n0 + srow0) * K + scol;
  const unsigned short* bp1 = Bbase + (long)(n0 + srow1) * K + scol;
  const unsigned short* cp0 = nullptr; const unsigned short* cp1 = nullptr;
  if constexpr (MODE == 0) {
    cp0 = B2 + (long)(n0 + srow0) * K + scol;
    cp1 = B2 + (long)(n0 + srow1) * K + scol;
  }

  unsigned short* AsW = &As[wave * 512];
  unsigned short* BsW = &Bs[wave * 512];
  unsigned short* CsW = nullptr;
  if constexpr (MODE == 0) CsW = &Cs[wave * 512];

  f32x4 acc[4][4];
  f32x4 acc2[(MODE == 0) ? 4 : 1][(MODE == 0) ? 4 : 1];
#pragma unroll
  for (int i = 0; i < 4; ++i) {
#pragma unroll
    for (int j = 0; j < 4; ++j) {
      acc[i][j] = {0.f, 0.f, 0.f, 0.f};
      if constexpr (MODE == 0) acc2[i][j] = {0.f, 0.f, 0.f, 0.f};
    }
  }

  const int KT = K >> 5;
  for (int kt = 0; kt < KT; ++kt) {
    const int ko = kt << 5;
    async_cp16(AsW,        ap0 + ko);
    async_cp16(AsW + 2048, ap1 + ko);
    async_cp16(BsW,        bp0 + ko);
    async_cp16(BsW + 2048, bp1 + ko);
    if constexpr (MODE == 0) {
      async_cp16(CsW,        cp0 + ko);
      async_cp16(CsW + 2048, cp1 + ko);
    }
    __syncthreads();

    bf16x8 af[4], bfr[4], cfr[(MODE == 0) ? 4 : 1];
#pragma unroll
    for (int mi = 0; mi < 4; ++mi)
      af[mi] = *(const bf16x8*)&As[(wm * 64 + mi * 16 + l16) * 32 + quad * 8];
#pragma unroll
    for (int ni = 0; ni < 4; ++ni) {
      bfr[ni] = *(const bf16x8*)&Bs[(wn * 64 + ni * 16 + l16) * 32 + quad * 8];
      if constexpr (MODE == 0)
        cfr[ni] = *(const bf16x8*)&Cs[(wn * 64 + ni * 16 + l16) * 32 + quad * 8];
    }
#pragma unroll
    for (int mi = 0; mi < 4; ++mi) {
#pragma unroll
      for (int ni = 0; ni < 4; ++ni) {
        acc[mi][ni] = __builtin_amdgcn_mfma_f32_16x16x32_bf16(
            af[mi], bfr[ni], acc[mi][ni], 0, 0, 0);
        if constexpr (MODE == 0)
          acc2[mi][ni] = __builtin_amdgcn_mfma_f32_16x16x32_bf16(
              af[mi], cfr[ni], acc2[mi][ni], 0, 0, 0);
      }
    }
    __syncthreads();
  }

  // epilogue; C/D layout: row = quad*4 + reg, col = lane&15 (m89-verified)
#pragma unroll
  for (int mi = 0; mi < 4; ++mi) {
#pragma unroll
    for (int r = 0; r < 4; ++r) {
      const int row = m0 + wm * 64 + mi * 16 + quad * 4 + r;
      if constexpr (MODE == 3) {
        unsigned short* yr = yrow(ylo, yhi, row);
#pragma unroll
        for (int ni = 0; ni < 4; ++ni) {
          const int c = n0 + wn * 64 + ni * 16 + l16;
          yr[c] = f2bf(acc[mi][ni][r] + bias[c]);
        }
      } else if constexpr (MODE == 4) {
        if (row < cnt_end) {
          const int t = slot_tok[row] >> 1;
          const float w = wts[row];            // slot_wt passed in wts param
#pragma unroll
          for (int ni = 0; ni < 4; ++ni) {
            const int c = n0 + wn * 64 + ni * 16 + l16;
            atomicAdd(&outF[(long)t * DH + c], w * (acc[mi][ni][r] + bias[c]));
          }
        }
      } else if constexpr (MODE == 2) {
        const int s0 = slot_pos[2 * row], s1 = slot_pos[2 * row + 1];
        const float w0 = wts[2 * row], w1 = wts[2 * row + 1];
        const unsigned short* y0 = yrow(ylo, yhi, s0);
        const unsigned short* y1 = yrow(ylo, yhi, s1);
#pragma unroll
        for (int ni = 0; ni < 4; ++ni) {
          const int c = n0 + wn * 64 + ni * 16 + l16;
          outF[(long)row * DH + c] =
              acc[mi][ni][r] + bias[c] + w0 * bf2f(y0[c]) + w1 * bf2f(y1[c]);
        }
      } else if constexpr (MODE == 5) {
#pragma unroll
        for (int ni = 0; ni < 4; ++ni) {
          const int c = n0 + wn * 64 + ni * 16 + l16;
          outF[(long)row * DH + c] = acc[mi][ni][r] + bias[c];
        }
      } else if constexpr (MODE == 1) {
#pragma unroll
        for (int ni = 0; ni < 4; ++ni) {
          const int c = n0 + wn * 64 + ni * 16 + l16;
          outH[(long)row * DF + c] = f2bf(gelu_exact(acc[mi][ni][r] + bias[c]));
        }
      } else {
#pragma unroll
        for (int ni = 0; ni < 4; ++ni) {
          const int c = n0 + wn * 64 + ni * 16 + l16;
          const float h1 = acc[mi][ni][r] + bias[c];
          const float h3 = acc2[mi][ni][r] + bias2[c];
          outH[(long)row * DF + c] = f2bf(gelu_exact(h1) * h3);
        }
      }
    }
  }
}

// ---------------------------------------------------------------------------
extern "C" void kernel_launch(void* const* d_in, const int* in_sizes, int n_in,
                              void* d_out, int out_size, void* d_ws, size_t ws_size,
                              hipStream_t stream) {
  const float* x     = (const float*)d_in[0];
  const float* gw    = (const float*)d_in[1];
  const float* fc1w  = (const float*)d_in[2];
  const float* fc1bs = (const float*)d_in[3];
  const float* fc2w  = (const float*)d_in[4];
  const float* fc2bs = (const float*)d_in[5];
  const float* w1w   = (const float*)d_in[6];
  const float* w1bs  = (const float*)d_in[7];
  const float* w3w   = (const float*)d_in[8];
  const float* w3bs  = (const float*)d_in[9];
  const float* w2w   = (const float*)d_in[10];
  const float* w2bs  = (const float*)d_in[11];
  float* out = (float*)d_out;

  char* p = (char*)d_ws;
  auto take = [&](size_t b) { char* r = p; p += (b + 255) & ~(size_t)255; return r; };
  unsigned short* xb   = (unsigned short*)take((size_t)T_TOK * DH * 2);
  unsigned short* fc1b = (unsigned short*)take((size_t)NE * DF * DH * 2);
  unsigned short* fc2b = (unsigned short*)take((size_t)NE * DH * DF * 2);
  unsigned short* w1b  = (unsigned short*)take((size_t)DF * DH * 2);
  unsigned short* w3b  = (unsigned short*)take((size_t)DF * DH * 2);
  unsigned short* w2b  = (unsigned short*)take((size_t)DH * DF * 2);
  unsigned short* h    = (unsigned short*)take((size_t)NROW_H * DF * 2);
  int*   eids     = (int*)take((size_t)NSLOT * 4);
  float* wts      = (float*)take((size_t)NSLOT * 4);
  int*   hcur     = (int*)take(NE * 64 * 4);
  int*   cur2     = (int*)take(NE * 64 * 4);
  int*   sched    = (int*)take(32 * 4);
  int*   slot_tok = (int*)take((size_t)NROW_H * 4);
  float* slot_wt  = (float*)take((size_t)NROW_H * 4);
  int*   slot_pos = (int*)take((size_t)NSLOT * 4);
  // common footprint: ~224.4e6 B (round-2-proven size)

  // path A extra: high rows of the routed-y buffer; low rows alias fc1b,
  // which is dead after routed fc1 (stream-ordered before routed fc2 writes y)
  const size_t yhi_bytes = (size_t)(NROW_H - T_TOK) * DH * 2;
  const bool pathA = ((size_t)(p - (char*)d_ws) + yhi_bytes) <= ws_size;
  unsigned short* ylo = fc1b;
  unsigned short* yhi = pathA ? (unsigned short*)take(yhi_bytes) : nullptr;

  hipMemsetAsync(hcur, 0, NE * 64 * sizeof(int), stream);

  auto conv = [&](const float* s, unsigned short* d, long n) {
    int n4 = (int)(n >> 2);
    conv_f32_bf16<<<(n4 + 255) / 256, 256, 0, stream>>>(s, d, n4);
  };
  conv(fc1w, fc1b, (long)NE * DF * DH);
  conv(fc2w, fc2b, (long)NE * DH * DF);
  conv(w1w, w1b, (long)DF * DH);
  conv(w3w, w3b, (long)DF * DH);
  conv(w2w, w2b, (long)DH * DF);

  // gate: topk (no atomics) -> histogram -> scan -> scatter
  gate_topk<<<T_TOK / 4, 256, 0, stream>>>(x, gw, xb, eids, wts);
  hist_k<<<NSLOT / 256, 256, 0, stream>>>(eids, hcur);
  scan_k<<<1, 64, 0, stream>>>(hcur, sched, cur2);
  scatter_k<<<NSLOT / 256, 256, 0, stream>>>(eids, wts, cur2, slot_tok, slot_wt,
                                             slot_pos);

  if (pathA) {
    // routed fc1 -> routed fc2 (y rows) -> shared fc1 -> shared fc2+combine
    gemm_k<1, 16, 16 * MT_ROUTED><<<16 * MT_ROUTED, 256, 0, stream>>>(
        xb, fc1b, nullptr, fc1bs, nullptr, nullptr, h, DH,
        sched, slot_tok, nullptr, nullptr, nullptr, nullptr);
    gemm_k<3, 6, 6 * MT_ROUTED><<<6 * MT_ROUTED, 256, 0, stream>>>(
        h, fc2b, nullptr, fc2bs, nullptr, nullptr, nullptr, DF,
        sched, nullptr, nullptr, nullptr, ylo, yhi);
    gemm_k<0, 16, 16 * (T_TOK / 128)><<<16 * (T_TOK / 128), 256, 0, stream>>>(
        xb, w1b, w3b, w1bs, w3bs, nullptr, h, DH,
        nullptr, nullptr, nullptr, nullptr, nullptr, nullptr);
    gemm_k<2, 6, 6 * (T_TOK / 128)><<<6 * (T_TOK / 128), 256, 0, stream>>>(
        h, w2b, nullptr, w2bs, nullptr, out, nullptr, DF,
        nullptr, nullptr, slot_pos, wts, ylo, yhi);
  } else {
    // fallback (round-2-proven footprint/order): shared plain, routed atomic
    gemm_k<0, 16, 16 * (T_TOK / 128)><<<16 * (T_TOK / 128), 256, 0, stream>>>(
        xb, w1b, w3b, w1bs, w3bs, nullptr, h, DH,
        nullptr, nullptr, nullptr, nullptr, nullptr, nullptr);
    gemm_k<5, 6, 6 * (T_TOK / 128)><<<6 * (T_TOK / 128), 256, 0, stream>>>(
        h, w2b, nullptr, w2bs, nullptr, out, nullptr, DF,
        nullptr, nullptr, nullptr, nullptr, nullptr, nullptr);
    gemm_k<1, 16, 16 * MT_ROUTED><<<16 * MT_ROUTED, 256, 0, stream>>>(
        xb, fc1b, nullptr, fc1bs, nullptr, nullptr, h, DH,
        sched, slot_tok, nullptr, nullptr, nullptr, nullptr);
    gemm_k<4, 6, 6 * MT_ROUTED><<<6 * MT_ROUTED, 256, 0, stream>>>(
        h, fc2b, nullptr, fc2bs, nullptr, out, nullptr, DF,
        sched, slot_tok, nullptr, slot_wt, nullptr, nullptr);
  }
}